// Round 4
// baseline (228.564 us; speedup 1.0000x reference)
//
#include <hip/hip_runtime.h>
#include <hip/hip_bf16.h>
#include <math.h>

typedef short v8s __attribute__((ext_vector_type(8)));
typedef short v4s __attribute__((ext_vector_type(4)));
typedef float v4f __attribute__((ext_vector_type(4)));
typedef unsigned short ushort_t;

__device__ __forceinline__ unsigned short f2bf(float f) {
    unsigned int u = __float_as_uint(f);
    u = (u + 0x7FFFu + ((u >> 16) & 1u)) >> 16;   // RNE
    return (unsigned short)u;
}

__device__ __forceinline__ void load_lds16(const void* g, void* l) {
    __builtin_amdgcn_global_load_lds((const __attribute__((address_space(1))) void*)g,
                                     (__attribute__((address_space(3))) void*)l,
                                     16, 0, 0);
}

#define FENCE() asm volatile("" ::: "memory")
#define BAR() do { FENCE(); __builtin_amdgcn_s_barrier(); FENCE(); } while (0)

// ---------------------------------------------------------------------------
__global__ __launch_bounds__(256) void cvt_kernel(const float4* __restrict__ in,
                                                  ushort_t* __restrict__ out, int n4) {
    int i = blockIdx.x * 256 + threadIdx.x;
    int stride = gridDim.x * 256;
    for (; i < n4; i += stride) {
        float4 v = in[i];
        v4s p;
        p[0] = (short)f2bf(v.x); p[1] = (short)f2bf(v.y);
        p[2] = (short)f2bf(v.z); p[3] = (short)f2bf(v.w);
        *(v4s*)(out + (size_t)i * 4) = p;
    }
}

// ---------------------------------------------------------------------------
__global__ void transpose_w(const float* __restrict__ W0, const float* __restrict__ W1,
                            const float* __restrict__ W2, ushort_t* __restrict__ WtAll) {
    const float* W = (blockIdx.z == 0) ? W0 : (blockIdx.z == 1 ? W1 : W2);
    ushort_t* out = WtAll + (size_t)blockIdx.z * 1024 * 1024;
    __shared__ float tile[32][33];
    int n0 = blockIdx.x * 32, k0 = blockIdx.y * 32;
    int tx = threadIdx.x, ty = threadIdx.y;       // block (32, 8)
    #pragma unroll
    for (int i = 0; i < 32; i += 8)
        tile[ty + i][tx] = W[(size_t)(k0 + ty + i) * 1024 + n0 + tx];
    __syncthreads();
    #pragma unroll
    for (int i = 0; i < 32; i += 8)
        out[(size_t)(n0 + ty + i) * 1024 + k0 + tx] = f2bf(tile[tx][ty + i]);
}

// ---------------------------------------------------------------------------
// Fused QKV projection, 256x256 tile, BK=64, 8 waves (2Mx4N), 8-phase
// schedule (4 phases per K-tile, 2 barriers/phase, counted vmcnt never 0).
// Stage order per tile t+1 (one quarter-pair per phase): B01, B23, A02, A13.
// Ledger (steady state, per-wave outstanding loads at the wait):
//   ph0: [A02(t),A13(t),B01(t+1)]=6 -> vmcnt(4): A02(t) landed (need: A-q0/q2 + all B)
//   ph1: [A13(t),B01(t+1),B23(t+1)]=6 -> vmcnt(4): A13(t) landed (need: A-q1/q3)
//   ph2/ph3: no new data needed -> no wait.
// Last tile: no stages -> vmcnt(2)/vmcnt(0).
__global__ __launch_bounds__(512)
void gemm_qkv8(const ushort_t* __restrict__ A, const ushort_t* __restrict__ Bt,
               const float* __restrict__ bq, const float* __restrict__ bk,
               const float* __restrict__ bv,
               ushort_t* __restrict__ Qb, ushort_t* __restrict__ Kb,
               ushort_t* __restrict__ Vt)
{
    int f = blockIdx.x;                        // 384 = 8*48
    int swz = (f & 7) * 48 + (f >> 3);
    const int bx = swz / 32, by = swz % 32;    // 12 x 32

    const int tid = threadIdx.x;
    const int lane = tid & 63, wid = tid >> 6;
    const int wm = wid >> 2, wc = wid & 3;     // 2 x 4 wave grid

    __shared__ ushort_t As[2][256 * 64];       // 64 KB
    __shared__ ushort_t Bs[2][256 * 64];       // 64 KB

    const int brow = by * 256, bcol = bx * 256;
    const int nt = 16;                         // K = 1024 / 64

    v4f acc[8][4];
    #pragma unroll
    for (int mi = 0; mi < 8; ++mi)
        #pragma unroll
        for (int ni = 0; ni < 4; ++ni)
            acc[mi][ni] = (v4f)0.f;

    const int sr = lane >> 3;                  // 0..7
    const int sl = lane & 7;                   // 16B slot

    // stage two 64-row quarters (2 loads/thread); LDS dest linear,
    // global source col pre-swizzled to match the read-side XOR.
    auto ST = [&](const ushort_t* G, int gbase, ushort_t* L, int k0, int q0, int q1) {
        #pragma unroll
        for (int c = 0; c < 2; ++c) {
            int qb = (c ? q1 : q0) * 64;
            int r = qb + wid * 8 + sr;
            int scol = ((sl ^ (r & 7)) << 3);
            load_lds16(G + (size_t)(gbase + r) * 1024 + k0 + scol,
                       L + (size_t)(qb + wid * 8) * 64);
        }
    };

    const int frow = lane & 15, fq4 = lane >> 4;
    const int axor = (frow & 7) << 3;

    // prologue: full tile 0 in canonical order
    ST(Bt, bcol, &Bs[0][0], 0, 0, 1);
    ST(Bt, bcol, &Bs[0][0], 0, 2, 3);
    ST(A,  brow, &As[0][0], 0, 0, 2);
    ST(A,  brow, &As[0][0], 0, 1, 3);

    for (int t = 0; t < nt; ++t) {
        const int cur = t & 1;
        const int k1 = (t + 1) * 64;
        const ushort_t* Ac = &As[cur][0];
        const ushort_t* Bc = &Bs[cur][0];
        ushort_t* An = &As[cur ^ 1][0];
        ushort_t* Bn = &Bs[cur ^ 1][0];
        v8s a[4], b[4];

        // ---- phase 0: cluster (mi 0-3, kk=0)
        if (t + 1 < nt) {
            ST(Bt, bcol, Bn, k1, 0, 1);
            asm volatile("s_waitcnt vmcnt(4)" ::: "memory");
        } else {
            asm volatile("s_waitcnt vmcnt(2)" ::: "memory");
        }
        BAR();
        {
            const int csw = (fq4 * 8) ^ axor;
            #pragma unroll
            for (int ni = 0; ni < 4; ++ni)
                b[ni] = *(const v8s*)(Bc + (size_t)(wc * 64 + ni * 16 + frow) * 64 + csw);
            #pragma unroll
            for (int i = 0; i < 4; ++i)
                a[i] = *(const v8s*)(Ac + (size_t)(wm * 128 + i * 16 + frow) * 64 + csw);
            __builtin_amdgcn_s_setprio(1);
            #pragma unroll
            for (int i = 0; i < 4; ++i)
                #pragma unroll
                for (int ni = 0; ni < 4; ++ni)
                    acc[i][ni] = __builtin_amdgcn_mfma_f32_16x16x32_bf16(a[i], b[ni], acc[i][ni], 0, 0, 0);
            __builtin_amdgcn_s_setprio(0);
        }
        BAR();

        // ---- phase 1: cluster (mi 4-7, kk=0), b held
        if (t + 1 < nt) {
            ST(Bt, bcol, Bn, k1, 2, 3);
            asm volatile("s_waitcnt vmcnt(4)" ::: "memory");
        } else {
            asm volatile("s_waitcnt vmcnt(0)" ::: "memory");
        }
        BAR();
        {
            const int csw = (fq4 * 8) ^ axor;
            #pragma unroll
            for (int i = 0; i < 4; ++i)
                a[i] = *(const v8s*)(Ac + (size_t)(wm * 128 + 64 + i * 16 + frow) * 64 + csw);
            __builtin_amdgcn_s_setprio(1);
            #pragma unroll
            for (int i = 0; i < 4; ++i)
                #pragma unroll
                for (int ni = 0; ni < 4; ++ni)
                    acc[4 + i][ni] = __builtin_amdgcn_mfma_f32_16x16x32_bf16(a[i], b[ni], acc[4 + i][ni], 0, 0, 0);
            __builtin_amdgcn_s_setprio(0);
        }
        BAR();

        // ---- phase 2: cluster (mi 0-3, kk=1)
        if (t + 1 < nt) ST(A, brow, An, k1, 0, 2);
        BAR();
        {
            const int csw = (32 + fq4 * 8) ^ axor;
            #pragma unroll
            for (int ni = 0; ni < 4; ++ni)
                b[ni] = *(const v8s*)(Bc + (size_t)(wc * 64 + ni * 16 + frow) * 64 + csw);
            #pragma unroll
            for (int i = 0; i < 4; ++i)
                a[i] = *(const v8s*)(Ac + (size_t)(wm * 128 + i * 16 + frow) * 64 + csw);
            __builtin_amdgcn_s_setprio(1);
            #pragma unroll
            for (int i = 0; i < 4; ++i)
                #pragma unroll
                for (int ni = 0; ni < 4; ++ni)
                    acc[i][ni] = __builtin_amdgcn_mfma_f32_16x16x32_bf16(a[i], b[ni], acc[i][ni], 0, 0, 0);
            __builtin_amdgcn_s_setprio(0);
        }
        BAR();

        // ---- phase 3: cluster (mi 4-7, kk=1), b held
        if (t + 1 < nt) ST(A, brow, An, k1, 1, 3);
        BAR();
        {
            const int csw = (32 + fq4 * 8) ^ axor;
            #pragma unroll
            for (int i = 0; i < 4; ++i)
                a[i] = *(const v8s*)(Ac + (size_t)(wm * 128 + 64 + i * 16 + frow) * 64 + csw);
            __builtin_amdgcn_s_setprio(1);
            #pragma unroll
            for (int i = 0; i < 4; ++i)
                #pragma unroll
                for (int ni = 0; ni < 4; ++ni)
                    acc[4 + i][ni] = __builtin_amdgcn_mfma_f32_16x16x32_bf16(a[i], b[ni], acc[4 + i][ni], 0, 0, 0);
            __builtin_amdgcn_s_setprio(0);
        }
        BAR();
    }

    const int fr = lane & 15;
    const int fq = lane >> 4;
    const int route = bx >> 2;                 // 0=Q, 1=K, 2=V
    const int cbase = (bx & 3) * 256 + wc * 64;
    if (route < 2) {
        ushort_t* C = route ? Kb : Qb;
        const float* bias = route ? bk : bq;
        const float scale = route ? 1.0f : 0.03125f;
        #pragma unroll
        for (int ni = 0; ni < 4; ++ni) {
            int cg = cbase + ni * 16 + fr;
            float bb = bias[cg];
            #pragma unroll
            for (int mi = 0; mi < 8; ++mi) {
                int gr0 = brow + wm * 128 + mi * 16 + fq * 4;
                #pragma unroll
                for (int j = 0; j < 4; ++j)
                    C[(size_t)(gr0 + j) * 1024 + cg] = f2bf((acc[mi][ni][j] + bb) * scale);
            }
        }
    } else {
        #pragma unroll
        for (int ni = 0; ni < 4; ++ni) {
            int e = cbase + ni * 16 + fr;
            float bb = bv[e];
            #pragma unroll
            for (int mi = 0; mi < 8; ++mi) {
                int gr0 = brow + wm * 128 + mi * 16 + fq * 4;  // b*2048 + s
                int bbat = gr0 >> 11;
                int sl2 = gr0 & 2047;
                alignas(8) ushort_t tmp[4];
                #pragma unroll
                for (int j = 0; j < 4; ++j)
                    tmp[j] = f2bf(acc[mi][ni][j] + bb);
                *(v4s*)(Vt + (size_t)bbat * (1024 * 2048) + (size_t)e * 2048 + sl2) =
                    *(const v4s*)tmp;
            }
        }
    }
}

// ---------------------------------------------------------------------------
// 128x256 tile, BK=32, 48 KB LDS -> 2 blocks/CU co-resident; 1-tile-ahead
// counted vmcnt dbuf. MODE 2: causal QK^T (288 blocks). MODE 3: PV (256).
template <int MODE>
__global__ __launch_bounds__(512)
void gemm_kv(const ushort_t* __restrict__ A, int lda, long long strideA,
             const ushort_t* __restrict__ Bt, int ldb, long long strideB,
             float* __restrict__ Cout, int ldc, long long strideC, int K)
{
    int bx, by, bz;
    int f = blockIdx.x;
    if constexpr (MODE == 2) {
        int swz = (f & 7) * 36 + (f >> 3);     // 288 = 8*36 bijective
        bz = swz / 72; int t = swz % 72;
        int r = 0, c = 0;
        while (c + (r / 2 + 1) <= t) { c += r / 2 + 1; ++r; }
        by = r; bx = t - c;                    // cols per row-block: by/2+1
    } else {
        int swz = (f & 7) * 32 + (f >> 3);     // 256 = 8*32
        bz = swz >> 6; int rem = swz & 63;
        by = rem >> 2; bx = rem & 3;           // 16 x 4
    }

    const int tid = threadIdx.x;
    const int lane = tid & 63, wid = tid >> 6;
    const int wm = wid >> 2, wc = wid & 3;     // 2 x 4 -> per-wave 64x64

    const ushort_t* Ab = A + (size_t)bz * strideA;
    const ushort_t* Bb = Bt + (size_t)bz * strideB;

    __shared__ ushort_t As[2][128 * 32];       // 16 KB
    __shared__ ushort_t Bs[2][256 * 32];       // 32 KB

    const int brow = by * 128, bcol = bx * 256;

    int kEnd = K;
    if constexpr (MODE == 3) { int lim = (by + 1) * 128; kEnd = lim < K ? lim : K; }
    const int nt = kEnd / 32;

    v4f acc[4][4];
    #pragma unroll
    for (int mi = 0; mi < 4; ++mi)
        #pragma unroll
        for (int ni = 0; ni < 4; ++ni)
            acc[mi][ni] = (v4f)0.f;

    const int sr = lane >> 2, sl = lane & 3;   // 4 slots of 16B per 32-el row
    auto STAGE = [&](int buf, int k0) {
        {
            int r = wid * 16 + sr;
            int scol = ((sl ^ (r & 3)) << 3);
            load_lds16(Ab + (size_t)(brow + r) * lda + k0 + scol,
                       &As[buf][(size_t)(wid * 16) * 32]);
        }
        #pragma unroll
        for (int c = 0; c < 2; ++c) {
            int r = c * 128 + wid * 16 + sr;
            int scol = ((sl ^ (r & 3)) << 3);
            load_lds16(Bb + (size_t)(bcol + r) * ldb + k0 + scol,
                       &Bs[buf][(size_t)(c * 128 + wid * 16) * 32]);
        }
    };

    const int frow = lane & 15, fq4 = lane >> 4;
    const int csw = (fq4 * 8) ^ ((frow & 3) << 3);

    STAGE(0, 0);
    for (int t = 0; t < nt; ++t) {
        const int cur = t & 1;
        if (t + 1 < nt) {
            STAGE(cur ^ 1, (t + 1) * 32);
            asm volatile("s_waitcnt vmcnt(3)" ::: "memory");
        } else {
            asm volatile("s_waitcnt vmcnt(0)" ::: "memory");
        }
        BAR();
        const ushort_t* Ac = &As[cur][0];
        const ushort_t* Bc = &Bs[cur][0];
        v8s a[4], b[4];
        #pragma unroll
        for (int mi = 0; mi < 4; ++mi)
            a[mi] = *(const v8s*)(Ac + (size_t)(wm * 64 + mi * 16 + frow) * 32 + csw);
        #pragma unroll
        for (int ni = 0; ni < 4; ++ni)
            b[ni] = *(const v8s*)(Bc + (size_t)(wc * 64 + ni * 16 + frow) * 32 + csw);
        __builtin_amdgcn_s_setprio(1);
        #pragma unroll
        for (int mi = 0; mi < 4; ++mi)
            #pragma unroll
            for (int ni = 0; ni < 4; ++ni)
                acc[mi][ni] = __builtin_amdgcn_mfma_f32_16x16x32_bf16(a[mi], b[ni], acc[mi][ni], 0, 0, 0);
        __builtin_amdgcn_s_setprio(0);
        BAR();
    }

    float* C = Cout + (size_t)bz * strideC;
    const int fr = lane & 15;
    const int fq = lane >> 4;
    #pragma unroll
    for (int ni = 0; ni < 4; ++ni) {
        int gc = bcol + wc * 64 + ni * 16 + fr;
        #pragma unroll
        for (int mi = 0; mi < 4; ++mi) {
            int gr0 = brow + wm * 64 + mi * 16 + fq * 4;
            #pragma unroll
            for (int j = 0; j < 4; ++j)
                C[(size_t)(gr0 + j) * ldc + gc] = acc[mi][ni][j];
        }
    }
}

// ---------------------------------------------------------------------------
// causal row softmax; fp32 scores row -> bf16 P in place (row pitch 4096 bf16).
// Writes zeros up to Lw = round-up-128(i+1) — PV K-limit granularity is 128.
__global__ __launch_bounds__(256) void softmax_causal(float* __restrict__ Sc) {
    int row = blockIdx.x;                // b*2048 + i
    int b = row >> 11, i = row & 2047;
    float* srow = Sc + ((size_t)b * 2048 + i) * 2048;
    const int L = i + 1;
    const int Lw = ((i >> 7) + 1) << 7;
    __shared__ float vals[2048];
    __shared__ float red[8];
    int tid = threadIdx.x, lane = tid & 63, wid = tid >> 6;

    float mx = -3.0e38f;
    const int L4 = L >> 2;
    for (int j = tid; j < L4; j += 256) {
        float4 v = ((const float4*)srow)[j];
        ((float4*)vals)[j] = v;
        mx = fmaxf(fmaxf(mx, fmaxf(v.x, v.y)), fmaxf(v.z, v.w));
    }
    {
        int j = (L4 << 2) + tid;
        if (j < L) { float v = srow[j]; vals[j] = v; mx = fmaxf(mx, v); }
    }
    #pragma unroll
    for (int o = 32; o; o >>= 1) mx = fmaxf(mx, __shfl_down(mx, o));
    if (lane == 0) red[wid] = mx;
    __syncthreads();
    mx = fmaxf(fmaxf(red[0], red[1]), fmaxf(red[2], red[3]));

    float sum = 0.f;
    for (int j = tid; j < L; j += 256) {
        float e = __expf(vals[j] - mx);
        vals[j] = e;
        sum += e;
    }
    #pragma unroll
    for (int o = 32; o; o >>= 1) sum += __shfl_down(sum, o);
    if (lane == 0) red[wid + 4] = sum;
    __syncthreads();
    float inv = 1.f / (red[4] + red[5] + red[6] + red[7]);

    ushort_t* prow = (ushort_t*)srow;
    for (int j4 = tid; j4 * 4 < Lw; j4 += 256) {
        int j = j4 * 4;
        float4 v = ((const float4*)vals)[j4];
        v4s p;
        p[0] = (short)f2bf((j     < L) ? v.x * inv : 0.f);
        p[1] = (short)f2bf((j + 1 < L) ? v.y * inv : 0.f);
        p[2] = (short)f2bf((j + 2 < L) ? v.z * inv : 0.f);
        p[3] = (short)f2bf((j + 3 < L) ? v.w * inv : 0.f);
        *(v4s*)(prow + j) = p;
    }
}

// ---------------------------------------------------------------------------
extern "C" void kernel_launch(void* const* d_in, const int* in_sizes, int n_in,
                              void* d_out, int out_size, void* d_ws, size_t ws_size,
                              hipStream_t stream) {
    const float* x  = (const float*)d_in[0];
    // d_in[1] = additive causal mask: structurally known, not read.
    const float* Wq = (const float*)d_in[2];
    const float* bq = (const float*)d_in[3];
    const float* Wk = (const float*)d_in[4];
    const float* bk = (const float*)d_in[5];
    const float* Wv = (const float*)d_in[6];
    const float* bv = (const float*)d_in[7];

    ushort_t* xb = (ushort_t*)d_ws;                        // 16.78 MB
    ushort_t* Wt = xb + (size_t)8192 * 1024;               //  6.29 MB (3x1024x1024)
    ushort_t* Qb = Wt + (size_t)3 * 1024 * 1024;           // 16.78 MB (scaled 1/32)
    ushort_t* Kb = Qb + (size_t)8192 * 1024;               // 16.78 MB
    ushort_t* Vt = Kb + (size_t)8192 * 1024;               // 16.78 MB (4x[1024][2048])
    float*    Sc = (float*)(Vt + (size_t)8192 * 1024);     // 67.11 MB

    cvt_kernel<<<2048, 256, 0, stream>>>((const float4*)x, xb, 8192 * 1024 / 4);
    transpose_w<<<dim3(32, 32, 3), dim3(32, 8), 0, stream>>>(Wq, Wk, Wv, Wt);

    // fused QKV projection: [8192x1024] x [3072x1024]^T, 8-phase schedule
    gemm_qkv8<<<384, 512, 0, stream>>>(xb, Wt, bq, bk, bv, Qb, Kb, Vt);

    // scores = Q K^T (causal, 128x256 tiles, 288 blocks)
    gemm_kv<2><<<288, 512, 0, stream>>>(Qb, 1024, 2048LL * 1024,
                                        Kb, 1024, 2048LL * 1024,
                                        Sc, 2048, 2048LL * 2048, 1024);

    softmax_causal<<<8192, 256, 0, stream>>>(Sc);

    // O = P V (K limited per 128-row block; 256 blocks)
    gemm_kv<3><<<256, 512, 0, stream>>>((const ushort_t*)Sc, 4096, 2048LL * 4096,
                                        Vt, 2048, 2048LL * 1024,
                                        (float*)d_out, 1024, 2048LL * 1024, 2048);
    (void)in_sizes; (void)n_in; (void)out_size; (void)ws_size;
}

// Round 5
// 199.074 us; speedup vs baseline: 1.1481x; 1.1481x over previous
//
#include <hip/hip_runtime.h>
#include <hip/hip_bf16.h>
#include <math.h>

typedef short v8s __attribute__((ext_vector_type(8)));
typedef short v4s __attribute__((ext_vector_type(4)));
typedef float v4f __attribute__((ext_vector_type(4)));
typedef unsigned short ushort_t;

__device__ __forceinline__ unsigned short f2bf(float f) {
    unsigned int u = __float_as_uint(f);
    u = (u + 0x7FFFu + ((u >> 16) & 1u)) >> 16;   // RNE
    return (unsigned short)u;
}

__device__ __forceinline__ void load_lds16(const void* g, void* l) {
    __builtin_amdgcn_global_load_lds((const __attribute__((address_space(1))) void*)g,
                                     (__attribute__((address_space(3))) void*)l,
                                     16, 0, 0);
}

#define FENCE() asm volatile("" ::: "memory")
#define BAR() do { FENCE(); __builtin_amdgcn_s_barrier(); FENCE(); } while (0)

// ---------------------------------------------------------------------------
__global__ __launch_bounds__(256) void cvt_kernel(const float4* __restrict__ in,
                                                  ushort_t* __restrict__ out, int n4) {
    int i = blockIdx.x * 256 + threadIdx.x;
    int stride = gridDim.x * 256;
    for (; i < n4; i += stride) {
        float4 v = in[i];
        v4s p;
        p[0] = (short)f2bf(v.x); p[1] = (short)f2bf(v.y);
        p[2] = (short)f2bf(v.z); p[3] = (short)f2bf(v.w);
        *(v4s*)(out + (size_t)i * 4) = p;
    }
}

// ---------------------------------------------------------------------------
__global__ void transpose_w(const float* __restrict__ W0, const float* __restrict__ W1,
                            const float* __restrict__ W2, ushort_t* __restrict__ WtAll) {
    const float* W = (blockIdx.z == 0) ? W0 : (blockIdx.z == 1 ? W1 : W2);
    ushort_t* out = WtAll + (size_t)blockIdx.z * 1024 * 1024;
    __shared__ float tile[32][33];
    int n0 = blockIdx.x * 32, k0 = blockIdx.y * 32;
    int tx = threadIdx.x, ty = threadIdx.y;       // block (32, 8)
    #pragma unroll
    for (int i = 0; i < 32; i += 8)
        tile[ty + i][tx] = W[(size_t)(k0 + ty + i) * 1024 + n0 + tx];
    __syncthreads();
    #pragma unroll
    for (int i = 0; i < 32; i += 8)
        out[(size_t)(n0 + ty + i) * 1024 + k0 + tx] = f2bf(tile[tx][ty + i]);
}

// ---------------------------------------------------------------------------
// Fused QKV projection, 256x256 tile, BK=64, 8 waves (2Mx4N), m201-style
// 4-phase-per-K-tile schedule. Phase = (m-half, kk): 16 MFMA each.
// Stage of tile t+1 into the dead buffer: A(both halves)@ph0, B0@ph1, B1@ph2.
// Single counted wait per K-tile: vmcnt(4) at ph0 (outstanding there =
// {B0(t),B1(t)}[landed-checked] + {A0A1(t+1)}[4, kept in flight]).
// ph0 reads post-barrier (fresh region); ph1-3 reads PRE-barrier (validated
// at ph0's barrier) so ds_read latency hides under other waves' MFMA.
__global__ __launch_bounds__(512)
void gemm_qkv8(const ushort_t* __restrict__ A, const ushort_t* __restrict__ Bt,
               const float* __restrict__ bq, const float* __restrict__ bk,
               const float* __restrict__ bv,
               ushort_t* __restrict__ Qb, ushort_t* __restrict__ Kb,
               ushort_t* __restrict__ Vt)
{
    // XCD-chunked by M-stripes: each XCD owns 4 consecutive by x all 12 bx
    // -> per-XCD: A stripe 2MB (L2-resident), Wt 6.3MB (L2/L3).
    int f = blockIdx.x;                        // 384 = 8 * 48
    int xcd = f & 7, i = f >> 3;               // i: 0..47
    const int by = xcd * 4 + i / 12;
    const int bx = i % 12;

    const int tid = threadIdx.x;
    const int lane = tid & 63, wid = tid >> 6;
    const int wm = wid >> 2, wc = wid & 3;     // 2 x 4 wave grid

    __shared__ ushort_t As[2][256 * 64];       // 64 KB
    __shared__ ushort_t Bs[2][256 * 64];       // 64 KB

    const int brow = by * 256, bcol = bx * 256;
    const int nt = 16;                         // K = 1024 / 64

    v4f acc[8][4];
    #pragma unroll
    for (int mi = 0; mi < 8; ++mi)
        #pragma unroll
        for (int ni = 0; ni < 4; ++ni)
            acc[mi][ni] = (v4f)0.f;

    const int sr = lane >> 3;                  // 0..7
    const int sl = lane & 7;                   // 16B slot

    // stage one 128-row half-tile (2 loads/thread); LDS dest linear,
    // global source col pre-swizzled to match the read-side XOR.
    auto ST = [&](const ushort_t* G, int gbase, ushort_t* L, int k0, int h) {
        #pragma unroll
        for (int c = 0; c < 2; ++c) {
            int r = h * 128 + c * 64 + wid * 8 + sr;
            int scol = ((sl ^ (r & 7)) << 3);
            load_lds16(G + (size_t)(gbase + r) * 1024 + k0 + scol,
                       L + (size_t)(h * 128 + c * 64 + wid * 8) * 64);
        }
    };

    const int frow = lane & 15, fq4 = lane >> 4;
    const int axor = (frow & 7) << 3;

    // prologue: full tile 0
    ST(A,  brow, &As[0][0], 0, 0);
    ST(A,  brow, &As[0][0], 0, 1);
    ST(Bt, bcol, &Bs[0][0], 0, 0);
    ST(Bt, bcol, &Bs[0][0], 0, 1);

    v8s b[4];

    for (int t = 0; t < nt; ++t) {
        const int cur = t & 1;
        const ushort_t* Ac = &As[cur][0];
        const ushort_t* Bc = &Bs[cur][0];
        ushort_t* An = &As[cur ^ 1][0];
        ushort_t* Bn = &Bs[cur ^ 1][0];
        const int k1 = (t + 1) * 64;
        const bool pf = (t + 1 < nt);

        // ===== ph0 (mh=0, kk=0): stage A(t+1); validate tile t; reads post-bar
        if (pf) {
            ST(A, brow, An, k1, 0);
            ST(A, brow, An, k1, 1);
            asm volatile("s_waitcnt vmcnt(4)" ::: "memory");
        } else {
            asm volatile("s_waitcnt vmcnt(0)" ::: "memory");
        }
        BAR();
        {
            const int csw = (fq4 * 8) ^ axor;
            #pragma unroll
            for (int ni = 0; ni < 4; ++ni)
                b[ni] = *(const v8s*)(Bc + (size_t)(wc * 64 + ni * 16 + frow) * 64 + csw);
            v8s a[4];
            #pragma unroll
            for (int mi = 0; mi < 4; ++mi)
                a[mi] = *(const v8s*)(Ac + (size_t)(wm * 128 + mi * 16 + frow) * 64 + csw);
            __builtin_amdgcn_s_setprio(1);
            #pragma unroll
            for (int mi = 0; mi < 4; ++mi)
                #pragma unroll
                for (int ni = 0; ni < 4; ++ni)
                    acc[mi][ni] = __builtin_amdgcn_mfma_f32_16x16x32_bf16(a[mi], b[ni], acc[mi][ni], 0, 0, 0);
            __builtin_amdgcn_s_setprio(0);
        }
        BAR();

        // ===== ph1 (mh=1, kk=0): reads pre-bar; stage B0(t+1); b held
        {
            const int csw = (fq4 * 8) ^ axor;
            v8s a[4];
            #pragma unroll
            for (int mi = 0; mi < 4; ++mi)
                a[mi] = *(const v8s*)(Ac + (size_t)(wm * 128 + 64 + mi * 16 + frow) * 64 + csw);
            if (pf) ST(Bt, bcol, Bn, k1, 0);
            BAR();
            __builtin_amdgcn_s_setprio(1);
            #pragma unroll
            for (int mi = 0; mi < 4; ++mi)
                #pragma unroll
                for (int ni = 0; ni < 4; ++ni)
                    acc[4 + mi][ni] = __builtin_amdgcn_mfma_f32_16x16x32_bf16(a[mi], b[ni], acc[4 + mi][ni], 0, 0, 0);
            __builtin_amdgcn_s_setprio(0);
        }
        BAR();

        // ===== ph2 (mh=0, kk=1): reads pre-bar; stage B1(t+1)
        {
            const int csw = (32 + fq4 * 8) ^ axor;
            #pragma unroll
            for (int ni = 0; ni < 4; ++ni)
                b[ni] = *(const v8s*)(Bc + (size_t)(wc * 64 + ni * 16 + frow) * 64 + csw);
            v8s a[4];
            #pragma unroll
            for (int mi = 0; mi < 4; ++mi)
                a[mi] = *(const v8s*)(Ac + (size_t)(wm * 128 + mi * 16 + frow) * 64 + csw);
            if (pf) ST(Bt, bcol, Bn, k1, 1);
            BAR();
            __builtin_amdgcn_s_setprio(1);
            #pragma unroll
            for (int mi = 0; mi < 4; ++mi)
                #pragma unroll
                for (int ni = 0; ni < 4; ++ni)
                    acc[mi][ni] = __builtin_amdgcn_mfma_f32_16x16x32_bf16(a[mi], b[ni], acc[mi][ni], 0, 0, 0);
            __builtin_amdgcn_s_setprio(0);
        }
        BAR();

        // ===== ph3 (mh=1, kk=1): reads pre-bar; no stage
        {
            const int csw = (32 + fq4 * 8) ^ axor;
            v8s a[4];
            #pragma unroll
            for (int mi = 0; mi < 4; ++mi)
                a[mi] = *(const v8s*)(Ac + (size_t)(wm * 128 + 64 + mi * 16 + frow) * 64 + csw);
            BAR();
            __builtin_amdgcn_s_setprio(1);
            #pragma unroll
            for (int mi = 0; mi < 4; ++mi)
                #pragma unroll
                for (int ni = 0; ni < 4; ++ni)
                    acc[4 + mi][ni] = __builtin_amdgcn_mfma_f32_16x16x32_bf16(a[mi], b[ni], acc[4 + mi][ni], 0, 0, 0);
            __builtin_amdgcn_s_setprio(0);
        }
        BAR();
    }

    const int fr = lane & 15;
    const int fq = lane >> 4;
    const int route = bx >> 2;                 // 0=Q, 1=K, 2=V
    const int cbase = (bx & 3) * 256 + wc * 64;
    if (route < 2) {
        ushort_t* C = route ? Kb : Qb;
        const float* bias = route ? bk : bq;
        const float scale = route ? 1.0f : 0.03125f;
        #pragma unroll
        for (int ni = 0; ni < 4; ++ni) {
            int cg = cbase + ni * 16 + fr;
            float bb = bias[cg];
            #pragma unroll
            for (int mi = 0; mi < 8; ++mi) {
                int gr0 = brow + wm * 128 + mi * 16 + fq * 4;
                #pragma unroll
                for (int j = 0; j < 4; ++j)
                    C[(size_t)(gr0 + j) * 1024 + cg] = f2bf((acc[mi][ni][j] + bb) * scale);
            }
        }
    } else {
        #pragma unroll
        for (int ni = 0; ni < 4; ++ni) {
            int e = cbase + ni * 16 + fr;
            float bb = bv[e];
            #pragma unroll
            for (int mi = 0; mi < 8; ++mi) {
                int gr0 = brow + wm * 128 + mi * 16 + fq * 4;  // b*2048 + s
                int bbat = gr0 >> 11;
                int sl2 = gr0 & 2047;
                alignas(8) ushort_t tmp[4];
                #pragma unroll
                for (int j = 0; j < 4; ++j)
                    tmp[j] = f2bf(acc[mi][ni][j] + bb);
                *(v4s*)(Vt + (size_t)bbat * (1024 * 2048) + (size_t)e * 2048 + sl2) =
                    *(const v4s*)tmp;
            }
        }
    }
}

// ---------------------------------------------------------------------------
// 128x256 tile, BK=32, 48 KB LDS -> 2 blocks/CU co-resident; 1-tile-ahead
// counted vmcnt dbuf. MODE 2: causal QK^T (288 blocks). MODE 3: PV (256).
template <int MODE>
__global__ __launch_bounds__(512)
void gemm_kv(const ushort_t* __restrict__ A, int lda, long long strideA,
             const ushort_t* __restrict__ Bt, int ldb, long long strideB,
             float* __restrict__ Cout, int ldc, long long strideC, int K)
{
    int bx, by, bz;
    int f = blockIdx.x;
    if constexpr (MODE == 2) {
        int swz = (f & 7) * 36 + (f >> 3);     // 288 = 8*36 bijective
        bz = swz / 72; int t = swz % 72;
        int r = 0, c = 0;
        while (c + (r / 2 + 1) <= t) { c += r / 2 + 1; ++r; }
        by = r; bx = t - c;                    // cols per row-block: by/2+1
    } else {
        int swz = (f & 7) * 32 + (f >> 3);     // 256 = 8*32
        bz = swz >> 6; int rem = swz & 63;
        by = rem >> 2; bx = rem & 3;           // 16 x 4
    }

    const int tid = threadIdx.x;
    const int lane = tid & 63, wid = tid >> 6;
    const int wm = wid >> 2, wc = wid & 3;     // 2 x 4 -> per-wave 64x64

    const ushort_t* Ab = A + (size_t)bz * strideA;
    const ushort_t* Bb = Bt + (size_t)bz * strideB;

    __shared__ ushort_t As[2][128 * 32];       // 16 KB
    __shared__ ushort_t Bs[2][256 * 32];       // 32 KB

    const int brow = by * 128, bcol = bx * 256;

    int kEnd = K;
    if constexpr (MODE == 3) { int lim = (by + 1) * 128; kEnd = lim < K ? lim : K; }
    const int nt = kEnd / 32;

    v4f acc[4][4];
    #pragma unroll
    for (int mi = 0; mi < 4; ++mi)
        #pragma unroll
        for (int ni = 0; ni < 4; ++ni)
            acc[mi][ni] = (v4f)0.f;

    const int sr = lane >> 2, sl = lane & 3;   // 4 slots of 16B per 32-el row
    auto STAGE = [&](int buf, int k0) {
        {
            int r = wid * 16 + sr;
            int scol = ((sl ^ (r & 3)) << 3);
            load_lds16(Ab + (size_t)(brow + r) * lda + k0 + scol,
                       &As[buf][(size_t)(wid * 16) * 32]);
        }
        #pragma unroll
        for (int c = 0; c < 2; ++c) {
            int r = c * 128 + wid * 16 + sr;
            int scol = ((sl ^ (r & 3)) << 3);
            load_lds16(Bb + (size_t)(bcol + r) * ldb + k0 + scol,
                       &Bs[buf][(size_t)(c * 128 + wid * 16) * 32]);
        }
    };

    const int frow = lane & 15, fq4 = lane >> 4;
    const int csw = (fq4 * 8) ^ ((frow & 3) << 3);

    STAGE(0, 0);
    for (int t = 0; t < nt; ++t) {
        const int cur = t & 1;
        if (t + 1 < nt) {
            STAGE(cur ^ 1, (t + 1) * 32);
            asm volatile("s_waitcnt vmcnt(3)" ::: "memory");
        } else {
            asm volatile("s_waitcnt vmcnt(0)" ::: "memory");
        }
        BAR();
        const ushort_t* Ac = &As[cur][0];
        const ushort_t* Bc = &Bs[cur][0];
        v8s a[4], b[4];
        #pragma unroll
        for (int mi = 0; mi < 4; ++mi)
            a[mi] = *(const v8s*)(Ac + (size_t)(wm * 64 + mi * 16 + frow) * 32 + csw);
        #pragma unroll
        for (int ni = 0; ni < 4; ++ni)
            b[ni] = *(const v8s*)(Bc + (size_t)(wc * 64 + ni * 16 + frow) * 32 + csw);
        __builtin_amdgcn_s_setprio(1);
        #pragma unroll
        for (int mi = 0; mi < 4; ++mi)
            #pragma unroll
            for (int ni = 0; ni < 4; ++ni)
                acc[mi][ni] = __builtin_amdgcn_mfma_f32_16x16x32_bf16(a[mi], b[ni], acc[mi][ni], 0, 0, 0);
        __builtin_amdgcn_s_setprio(0);
        BAR();
    }

    float* C = Cout + (size_t)bz * strideC;
    const int fr = lane & 15;
    const int fq = lane >> 4;
    #pragma unroll
    for (int ni = 0; ni < 4; ++ni) {
        int gc = bcol + wc * 64 + ni * 16 + fr;
        #pragma unroll
        for (int mi = 0; mi < 4; ++mi) {
            int gr0 = brow + wm * 64 + mi * 16 + fq * 4;
            #pragma unroll
            for (int j = 0; j < 4; ++j)
                C[(size_t)(gr0 + j) * ldc + gc] = acc[mi][ni][j];
        }
    }
}

// ---------------------------------------------------------------------------
// causal row softmax; fp32 scores row -> bf16 P in place (row pitch 4096 bf16).
// Writes zeros up to Lw = round-up-128(i+1) — PV K-limit granularity is 128.
__global__ __launch_bounds__(256) void softmax_causal(float* __restrict__ Sc) {
    int row = blockIdx.x;                // b*2048 + i
    int b = row >> 11, i = row & 2047;
    float* srow = Sc + ((size_t)b * 2048 + i) * 2048;
    const int L = i + 1;
    const int Lw = ((i >> 7) + 1) << 7;
    __shared__ float vals[2048];
    __shared__ float red[8];
    int tid = threadIdx.x, lane = tid & 63, wid = tid >> 6;

    float mx = -3.0e38f;
    const int L4 = L >> 2;
    for (int j = tid; j < L4; j += 256) {
        float4 v = ((const float4*)srow)[j];
        ((float4*)vals)[j] = v;
        mx = fmaxf(fmaxf(mx, fmaxf(v.x, v.y)), fmaxf(v.z, v.w));
    }
    {
        int j = (L4 << 2) + tid;
        if (j < L) { float v = srow[j]; vals[j] = v; mx = fmaxf(mx, v); }
    }
    #pragma unroll
    for (int o = 32; o; o >>= 1) mx = fmaxf(mx, __shfl_down(mx, o));
    if (lane == 0) red[wid] = mx;
    __syncthreads();
    mx = fmaxf(fmaxf(red[0], red[1]), fmaxf(red[2], red[3]));

    float sum = 0.f;
    for (int j = tid; j < L; j += 256) {
        float e = __expf(vals[j] - mx);
        vals[j] = e;
        sum += e;
    }
    #pragma unroll
    for (int o = 32; o; o >>= 1) sum += __shfl_down(sum, o);
    if (lane == 0) red[wid + 4] = sum;
    __syncthreads();
    float inv = 1.f / (red[4] + red[5] + red[6] + red[7]);

    ushort_t* prow = (ushort_t*)srow;
    for (int j4 = tid; j4 * 4 < Lw; j4 += 256) {
        int j = j4 * 4;
        float4 v = ((const float4*)vals)[j4];
        v4s p;
        p[0] = (short)f2bf((j     < L) ? v.x * inv : 0.f);
        p[1] = (short)f2bf((j + 1 < L) ? v.y * inv : 0.f);
        p[2] = (short)f2bf((j + 2 < L) ? v.z * inv : 0.f);
        p[3] = (short)f2bf((j + 3 < L) ? v.w * inv : 0.f);
        *(v4s*)(prow + j) = p;
    }
}

// ---------------------------------------------------------------------------
extern "C" void kernel_launch(void* const* d_in, const int* in_sizes, int n_in,
                              void* d_out, int out_size, void* d_ws, size_t ws_size,
                              hipStream_t stream) {
    const float* x  = (const float*)d_in[0];
    // d_in[1] = additive causal mask: structurally known, not read.
    const float* Wq = (const float*)d_in[2];
    const float* bq = (const float*)d_in[3];
    const float* Wk = (const float*)d_in[4];
    const float* bk = (const float*)d_in[5];
    const float* Wv = (const float*)d_in[6];
    const float* bv = (const float*)d_in[7];

    ushort_t* xb = (ushort_t*)d_ws;                        // 16.78 MB
    ushort_t* Wt = xb + (size_t)8192 * 1024;               //  6.29 MB (3x1024x1024)
    ushort_t* Qb = Wt + (size_t)3 * 1024 * 1024;           // 16.78 MB (scaled 1/32)
    ushort_t* Kb = Qb + (size_t)8192 * 1024;               // 16.78 MB
    ushort_t* Vt = Kb + (size_t)8192 * 1024;               // 16.78 MB (4x[1024][2048])
    float*    Sc = (float*)(Vt + (size_t)8192 * 1024);     // 67.11 MB

    cvt_kernel<<<2048, 256, 0, stream>>>((const float4*)x, xb, 8192 * 1024 / 4);
    transpose_w<<<dim3(32, 32, 3), dim3(32, 8), 0, stream>>>(Wq, Wk, Wv, Wt);

    // fused QKV projection: [8192x1024] x [3072x1024]^T, faithful 8-phase
    gemm_qkv8<<<384, 512, 0, stream>>>(xb, Wt, bq, bk, bv, Qb, Kb, Vt);

    // scores = Q K^T (causal, 128x256 tiles, 288 blocks)
    gemm_kv<2><<<288, 512, 0, stream>>>(Qb, 1024, 2048LL * 1024,
                                        Kb, 1024, 2048LL * 1024,
                                        Sc, 2048, 2048LL * 2048, 1024);

    softmax_causal<<<8192, 256, 0, stream>>>(Sc);

    // O = P V (K limited per 128-row block; 256 blocks)
    gemm_kv<3><<<256, 512, 0, stream>>>((const ushort_t*)Sc, 4096, 2048LL * 4096,
                                        Vt, 2048, 2048LL * 1024,
                                        (float*)d_out, 1024, 2048LL * 1024, 2048);
    (void)in_sizes; (void)n_in; (void)out_size; (void)ws_size;
}

// Round 6
// 190.817 us; speedup vs baseline: 1.1978x; 1.0433x over previous
//
#include <hip/hip_runtime.h>
#include <hip/hip_bf16.h>
#include <math.h>

typedef short v8s __attribute__((ext_vector_type(8)));
typedef short v4s __attribute__((ext_vector_type(4)));
typedef float v4f __attribute__((ext_vector_type(4)));
typedef unsigned short ushort_t;

__device__ __forceinline__ unsigned short f2bf(float f) {
    unsigned int u = __float_as_uint(f);
    u = (u + 0x7FFFu + ((u >> 16) & 1u)) >> 16;   // RNE
    return (unsigned short)u;
}

__device__ __forceinline__ void load_lds16(const void* g, void* l) {
    __builtin_amdgcn_global_load_lds((const __attribute__((address_space(1))) void*)g,
                                     (__attribute__((address_space(3))) void*)l,
                                     16, 0, 0);
}

#define FENCE() asm volatile("" ::: "memory")
#define BAR() do { FENCE(); __builtin_amdgcn_s_barrier(); FENCE(); } while (0)

// ---------------------------------------------------------------------------
__global__ __launch_bounds__(256) void cvt_kernel(const float4* __restrict__ in,
                                                  ushort_t* __restrict__ out, int n4) {
    int i = blockIdx.x * 256 + threadIdx.x;
    int stride = gridDim.x * 256;
    for (; i < n4; i += stride) {
        float4 v = in[i];
        v4s p;
        p[0] = (short)f2bf(v.x); p[1] = (short)f2bf(v.y);
        p[2] = (short)f2bf(v.z); p[3] = (short)f2bf(v.w);
        *(v4s*)(out + (size_t)i * 4) = p;
    }
}

// ---------------------------------------------------------------------------
__global__ void transpose_w(const float* __restrict__ W0, const float* __restrict__ W1,
                            const float* __restrict__ W2, ushort_t* __restrict__ WtAll) {
    const float* W = (blockIdx.z == 0) ? W0 : (blockIdx.z == 1 ? W1 : W2);
    ushort_t* out = WtAll + (size_t)blockIdx.z * 1024 * 1024;
    __shared__ float tile[32][33];
    int n0 = blockIdx.x * 32, k0 = blockIdx.y * 32;
    int tx = threadIdx.x, ty = threadIdx.y;       // block (32, 8)
    #pragma unroll
    for (int i = 0; i < 32; i += 8)
        tile[ty + i][tx] = W[(size_t)(k0 + ty + i) * 1024 + n0 + tx];
    __syncthreads();
    #pragma unroll
    for (int i = 0; i < 32; i += 8)
        out[(size_t)(n0 + ty + i) * 1024 + k0 + tx] = f2bf(tile[tx][ty + i]);
}

// ---------------------------------------------------------------------------
// Unified ring-3 GEMM: 128x256 tile, BK=32, 8 waves (2Mx4N, per-wave 64x64),
// 72 KB LDS -> 2 blocks/CU co-resident. Counted-vmcnt pipeline: stage tile
// t+2 into buf (t+2)%3; steady wait vmcnt(6) (= 2 tiles x 3 loads in
// flight, never drained to 0 mid-loop); 2 barriers per K-tile.
// Race safety: stage at iter t writes buf(t+2)%3 = buf(t-1); all waves
// passed iter t-1's closing barrier before any wave issues that stage.
// MODE 0: fused QKV projection (routing epilogue, bf16 out)
// MODE 2: causal scores QK^T (fp32 out, triangular grid)
// MODE 3: PV (fp32 out, kEnd = (by+1)*128)
template <int MODE>
__global__ __launch_bounds__(512)
void gemm_ring(const ushort_t* __restrict__ A, int lda, long long strideA,
               const ushort_t* __restrict__ Bt, int ldb, long long strideB,
               const float* __restrict__ bq, const float* __restrict__ bk,
               const float* __restrict__ bv,
               ushort_t* __restrict__ Qb, ushort_t* __restrict__ Kb,
               ushort_t* __restrict__ Vt,
               float* __restrict__ Cf, int ldc, long long strideC, int K)
{
    int bx, by, bz = 0;
    int f = blockIdx.x;
    if constexpr (MODE == 0) {
        // 768 = 8 XCDs * 96; each XCD owns an 8-row M-stripe (A 2.1 MB, L2)
        int xcd = f & 7, i = f >> 3;
        by = xcd * 8 + i / 12;                 // 64 M-tiles
        bx = i % 12;                           // 12 N-tiles (3072 cols)
    } else if constexpr (MODE == 2) {
        int swz = (f & 7) * 36 + (f >> 3);     // 288 = 8*36 bijective
        bz = swz / 72; int t = swz % 72;
        int r = 0, c = 0;
        while (c + (r / 2 + 1) <= t) { c += r / 2 + 1; ++r; }
        by = r; bx = t - c;                    // cols per row-block: by/2+1
    } else {
        int swz = (f & 7) * 32 + (f >> 3);     // 256 = 8*32
        bz = swz >> 6; int rem = swz & 63;
        by = rem >> 2; bx = rem & 3;           // 16 x 4
    }

    const int tid = threadIdx.x;
    const int lane = tid & 63, wid = tid >> 6;
    const int wm = wid >> 2, wc = wid & 3;     // 2 x 4 -> per-wave 64x64

    const ushort_t* Ab = A + (size_t)bz * strideA;
    const ushort_t* Bb = Bt + (size_t)bz * strideB;

    __shared__ ushort_t As[3][128 * 32];       // 3 x 8 KB
    __shared__ ushort_t Bs[3][256 * 32];       // 3 x 16 KB  (total 72 KB)

    const int brow = by * 128, bcol = bx * 256;

    int kEnd = K;
    if constexpr (MODE == 3) { int lim = (by + 1) * 128; kEnd = lim < K ? lim : K; }
    const int nt = kEnd / 32;

    v4f acc[4][4];
    #pragma unroll
    for (int mi = 0; mi < 4; ++mi)
        #pragma unroll
        for (int ni = 0; ni < 4; ++ni)
            acc[mi][ni] = (v4f)0.f;

    const int rT = tid >> 2;                   // 0..127
    const int slot = tid & 3;                  // 16B slot in a 64B row
    // A: 128x32 (8 KB, 1 load/thread); B: 256x32 (16 KB, 2 loads/thread).
    // LDS dest linear; global source 16B-slot XOR-swizzled to match reads.
    auto STAGE = [&](int buf, int t) {
        const int k0 = t * 32;
        {
            int r = rT;
            int sc = ((slot ^ (r & 3)) << 3);
            load_lds16(Ab + (size_t)(brow + r) * lda + k0 + sc,
                       &As[buf][(size_t)(wid * 16) * 32]);
        }
        #pragma unroll
        for (int c = 0; c < 2; ++c) {
            int r = c * 128 + rT;
            int sc = ((slot ^ (r & 3)) << 3);
            load_lds16(Bb + (size_t)(bcol + r) * ldb + k0 + sc,
                       &Bs[buf][(size_t)(c * 128 + wid * 16) * 32]);
        }
    };

    const int frow = lane & 15, fq4 = lane >> 4;
    const int csw = (fq4 * 8) ^ ((frow & 3) << 3);

    STAGE(0, 0);
    if (nt > 1) STAGE(1, 1);

    int cur = 0;
    for (int t = 0; t < nt; ++t) {
        if (t + 2 < nt) {
            int tgt = cur ? cur - 1 : 2;       // (cur+2)%3
            STAGE(tgt, t + 2);
            asm volatile("s_waitcnt vmcnt(6)" ::: "memory");
        } else if (t + 1 < nt) {
            asm volatile("s_waitcnt vmcnt(3)" ::: "memory");
        } else {
            asm volatile("s_waitcnt vmcnt(0)" ::: "memory");
        }
        BAR();
        const ushort_t* Ac = &As[cur][0];
        const ushort_t* Bc = &Bs[cur][0];
        v8s a[4], b[4];
        #pragma unroll
        for (int mi = 0; mi < 4; ++mi)
            a[mi] = *(const v8s*)(Ac + (size_t)(wm * 64 + mi * 16 + frow) * 32 + csw);
        #pragma unroll
        for (int ni = 0; ni < 4; ++ni)
            b[ni] = *(const v8s*)(Bc + (size_t)(wc * 64 + ni * 16 + frow) * 32 + csw);
        __builtin_amdgcn_s_setprio(1);
        #pragma unroll
        for (int mi = 0; mi < 4; ++mi)
            #pragma unroll
            for (int ni = 0; ni < 4; ++ni)
                acc[mi][ni] = __builtin_amdgcn_mfma_f32_16x16x32_bf16(a[mi], b[ni], acc[mi][ni], 0, 0, 0);
        __builtin_amdgcn_s_setprio(0);
        BAR();
        cur = (cur == 2) ? 0 : cur + 1;
    }

    const int fr = lane & 15;
    const int fq = lane >> 4;

    if constexpr (MODE == 0) {
        const int route = bx >> 2;             // 0=Q, 1=K, 2=V (256-col tiles)
        const int cbase = (bx & 3) * 256 + wc * 64;
        if (route < 2) {
            ushort_t* C = route ? Kb : Qb;
            const float* bias = route ? bk : bq;
            const float scale = route ? 1.0f : 0.03125f;
            #pragma unroll
            for (int ni = 0; ni < 4; ++ni) {
                int cg = cbase + ni * 16 + fr;
                float bb = bias[cg];
                #pragma unroll
                for (int mi = 0; mi < 4; ++mi) {
                    int gr0 = brow + wm * 64 + mi * 16 + fq * 4;
                    #pragma unroll
                    for (int j = 0; j < 4; ++j)
                        C[(size_t)(gr0 + j) * 1024 + cg] = f2bf((acc[mi][ni][j] + bb) * scale);
                }
            }
        } else {
            #pragma unroll
            for (int ni = 0; ni < 4; ++ni) {
                int e = cbase + ni * 16 + fr;
                float bb = bv[e];
                #pragma unroll
                for (int mi = 0; mi < 4; ++mi) {
                    int gr0 = brow + wm * 64 + mi * 16 + fq * 4;   // b*2048 + s
                    int bbat = gr0 >> 11;
                    int sl2 = gr0 & 2047;
                    alignas(8) ushort_t tmp[4];
                    #pragma unroll
                    for (int j = 0; j < 4; ++j)
                        tmp[j] = f2bf(acc[mi][ni][j] + bb);
                    *(v4s*)(Vt + (size_t)bbat * (1024 * 2048) + (size_t)e * 2048 + sl2) =
                        *(const v4s*)tmp;
                }
            }
        }
    } else {
        float* C = Cf + (size_t)bz * strideC;
        #pragma unroll
        for (int ni = 0; ni < 4; ++ni) {
            int gc = bcol + wc * 64 + ni * 16 + fr;
            #pragma unroll
            for (int mi = 0; mi < 4; ++mi) {
                int gr0 = brow + wm * 64 + mi * 16 + fq * 4;
                #pragma unroll
                for (int j = 0; j < 4; ++j)
                    C[(size_t)(gr0 + j) * ldc + gc] = acc[mi][ni][j];
            }
        }
    }
}

// ---------------------------------------------------------------------------
// causal row softmax; fp32 scores row -> bf16 P in place (row pitch 4096 bf16).
// Writes zeros up to Lw = round-up-128(i+1) — PV K-limit granularity is 128.
__global__ __launch_bounds__(256) void softmax_causal(float* __restrict__ Sc) {
    int row = blockIdx.x;                // b*2048 + i
    int b = row >> 11, i = row & 2047;
    float* srow = Sc + ((size_t)b * 2048 + i) * 2048;
    const int L = i + 1;
    const int Lw = ((i >> 7) + 1) << 7;
    __shared__ float vals[2048];
    __shared__ float red[8];
    int tid = threadIdx.x, lane = tid & 63, wid = tid >> 6;

    float mx = -3.0e38f;
    const int L4 = L >> 2;
    for (int j = tid; j < L4; j += 256) {
        float4 v = ((const float4*)srow)[j];
        ((float4*)vals)[j] = v;
        mx = fmaxf(fmaxf(mx, fmaxf(v.x, v.y)), fmaxf(v.z, v.w));
    }
    {
        int j = (L4 << 2) + tid;
        if (j < L) { float v = srow[j]; vals[j] = v; mx = fmaxf(mx, v); }
    }
    #pragma unroll
    for (int o = 32; o; o >>= 1) mx = fmaxf(mx, __shfl_down(mx, o));
    if (lane == 0) red[wid] = mx;
    __syncthreads();
    mx = fmaxf(fmaxf(red[0], red[1]), fmaxf(red[2], red[3]));

    float sum = 0.f;
    for (int j = tid; j < L; j += 256) {
        float e = __expf(vals[j] - mx);
        vals[j] = e;
        sum += e;
    }
    #pragma unroll
    for (int o = 32; o; o >>= 1) sum += __shfl_down(sum, o);
    if (lane == 0) red[wid + 4] = sum;
    __syncthreads();
    float inv = 1.f / (red[4] + red[5] + red[6] + red[7]);

    ushort_t* prow = (ushort_t*)srow;
    for (int j4 = tid; j4 * 4 < Lw; j4 += 256) {
        int j = j4 * 4;
        float4 v = ((const float4*)vals)[j4];
        v4s p;
        p[0] = (short)f2bf((j     < L) ? v.x * inv : 0.f);
        p[1] = (short)f2bf((j + 1 < L) ? v.y * inv : 0.f);
        p[2] = (short)f2bf((j + 2 < L) ? v.z * inv : 0.f);
        p[3] = (short)f2bf((j + 3 < L) ? v.w * inv : 0.f);
        *(v4s*)(prow + j) = p;
    }
}

// ---------------------------------------------------------------------------
extern "C" void kernel_launch(void* const* d_in, const int* in_sizes, int n_in,
                              void* d_out, int out_size, void* d_ws, size_t ws_size,
                              hipStream_t stream) {
    const float* x  = (const float*)d_in[0];
    // d_in[1] = additive causal mask: structurally known, not read.
    const float* Wq = (const float*)d_in[2];
    const float* bq = (const float*)d_in[3];
    const float* Wk = (const float*)d_in[4];
    const float* bk = (const float*)d_in[5];
    const float* Wv = (const float*)d_in[6];
    const float* bv = (const float*)d_in[7];

    ushort_t* xb = (ushort_t*)d_ws;                        // 16.78 MB
    ushort_t* Wt = xb + (size_t)8192 * 1024;               //  6.29 MB (3x1024x1024)
    ushort_t* Qb = Wt + (size_t)3 * 1024 * 1024;           // 16.78 MB (scaled 1/32)
    ushort_t* Kb = Qb + (size_t)8192 * 1024;               // 16.78 MB
    ushort_t* Vt = Kb + (size_t)8192 * 1024;               // 16.78 MB (4x[1024][2048])
    float*    Sc = (float*)(Vt + (size_t)8192 * 1024);     // 67.11 MB

    cvt_kernel<<<2048, 256, 0, stream>>>((const float4*)x, xb, 8192 * 1024 / 4);
    transpose_w<<<dim3(32, 32, 3), dim3(32, 8), 0, stream>>>(Wq, Wk, Wv, Wt);

    // fused QKV projection: [8192x1024] x [3072x1024]^T, ring-3, 3 blocks/CU
    gemm_ring<0><<<768, 512, 0, stream>>>(xb, 1024, 0, Wt, 1024, 0,
                                          bq, bk, bv, Qb, Kb, Vt,
                                          nullptr, 0, 0, 1024);

    // scores = Q K^T (causal, 128x256 tiles, 288 blocks)
    gemm_ring<2><<<288, 512, 0, stream>>>(Qb, 1024, 2048LL * 1024,
                                          Kb, 1024, 2048LL * 1024,
                                          nullptr, nullptr, nullptr,
                                          nullptr, nullptr, nullptr,
                                          Sc, 2048, 2048LL * 2048, 1024);

    softmax_causal<<<8192, 256, 0, stream>>>(Sc);

    // O = P V (K limited per 128-row block; 256 blocks)
    gemm_ring<3><<<256, 512, 0, stream>>>((const ushort_t*)Sc, 4096, 2048LL * 4096,
                                          Vt, 2048, 2048LL * 1024,
                                          nullptr, nullptr, nullptr,
                                          nullptr, nullptr, nullptr,
                                          (float*)d_out, 1024, 2048LL * 1024, 2048);
    (void)in_sizes; (void)n_in; (void)out_size; (void)ws_size;
}

// Round 7
// 176.341 us; speedup vs baseline: 1.2962x; 1.0821x over previous
//
#include <hip/hip_runtime.h>
#include <hip/hip_bf16.h>
#include <math.h>

typedef short v8s __attribute__((ext_vector_type(8)));
typedef short v4s __attribute__((ext_vector_type(4)));
typedef float v4f __attribute__((ext_vector_type(4)));
typedef unsigned short ushort_t;

__device__ __forceinline__ unsigned short f2bf(float f) {
    unsigned int u = __float_as_uint(f);
    u = (u + 0x7FFFu + ((u >> 16) & 1u)) >> 16;   // RNE
    return (unsigned short)u;
}

__device__ __forceinline__ void load_lds16(const void* g, void* l) {
    __builtin_amdgcn_global_load_lds((const __attribute__((address_space(1))) void*)g,
                                     (__attribute__((address_space(3))) void*)l,
                                     16, 0, 0);
}

#define FENCE() asm volatile("" ::: "memory")
#define BAR() do { FENCE(); __builtin_amdgcn_s_barrier(); FENCE(); } while (0)

// ---------------------------------------------------------------------------
__global__ __launch_bounds__(256) void cvt_kernel(const float4* __restrict__ in,
                                                  ushort_t* __restrict__ out, int n4) {
    int i = blockIdx.x * 256 + threadIdx.x;
    int stride = gridDim.x * 256;
    for (; i < n4; i += stride) {
        float4 v = in[i];
        v4s p;
        p[0] = (short)f2bf(v.x); p[1] = (short)f2bf(v.y);
        p[2] = (short)f2bf(v.z); p[3] = (short)f2bf(v.w);
        *(v4s*)(out + (size_t)i * 4) = p;
    }
}

// ---------------------------------------------------------------------------
__global__ void transpose_w(const float* __restrict__ W0, const float* __restrict__ W1,
                            const float* __restrict__ W2, ushort_t* __restrict__ WtAll) {
    const float* W = (blockIdx.z == 0) ? W0 : (blockIdx.z == 1 ? W1 : W2);
    ushort_t* out = WtAll + (size_t)blockIdx.z * 1024 * 1024;
    __shared__ float tile[32][33];
    int n0 = blockIdx.x * 32, k0 = blockIdx.y * 32;
    int tx = threadIdx.x, ty = threadIdx.y;       // block (32, 8)
    #pragma unroll
    for (int i = 0; i < 32; i += 8)
        tile[ty + i][tx] = W[(size_t)(k0 + ty + i) * 1024 + n0 + tx];
    __syncthreads();
    #pragma unroll
    for (int i = 0; i < 32; i += 8)
        out[(size_t)(n0 + ty + i) * 1024 + k0 + tx] = f2bf(tile[tx][ty + i]);
}

// ---------------------------------------------------------------------------
// Ring-3 counted-vmcnt GEMM, BK=32, per-wave 64x64 output (acc 4x4).
// Swizzle: logical 16B-slot s of row r stored at slot s ^ ((r>>1)&3); banks
// spread over all 8 positions exactly 2x per 16-lane group (2-way = free).
// MODE 0: QKV projection, 512 thr, 128x256 tile, grid 768 (XCD M-stripes)
// MODE 2: causal QK^T,   512 thr, 128x256 tile, grid 288 (triangular)
// MODE 3: PV,            256 thr, 128x128 tile, grid 512 (2/CU, K-limited)
template <int MODE>
__global__ __launch_bounds__(MODE == 3 ? 256 : 512)
void gemm_ring(const ushort_t* __restrict__ A, int lda, long long strideA,
               const ushort_t* __restrict__ Bt, int ldb, long long strideB,
               const float* __restrict__ bq, const float* __restrict__ bk,
               const float* __restrict__ bv,
               ushort_t* __restrict__ Qb, ushort_t* __restrict__ Kb,
               ushort_t* __restrict__ Vt,
               float* __restrict__ Cf, int ldc, long long strideC, int K)
{
    constexpr int THREADS = (MODE == 3) ? 256 : 512;
    constexpr int BN      = (MODE == 3) ? 128 : 256;
    constexpr int NW      = THREADS / 64;     // 4 or 8 waves
    constexpr int RPL     = THREADS / 4;      // rows staged per code line
    constexpr int ALINES  = 128 / RPL;
    constexpr int BLINES  = BN / RPL;

    int bx, by, bz = 0;
    int f = blockIdx.x;
    if constexpr (MODE == 0) {
        // 768 = 8 XCDs * 96; each XCD owns an 8-row M-stripe (A 2.1 MB in L2)
        int xcd = f & 7, i = f >> 3;
        by = xcd * 8 + i / 12;                 // 64 M-tiles
        bx = i % 12;                           // 12 N-tiles of 256 (3072 cols)
    } else if constexpr (MODE == 2) {
        int swz = (f & 7) * 36 + (f >> 3);     // 288 = 8*36 bijective
        bz = swz / 72; int t = swz % 72;
        int r = 0, c = 0;
        while (c + (r / 2 + 1) <= t) { c += r / 2 + 1; ++r; }
        by = r; bx = t - c;                    // cols per row-block: by/2+1
    } else {
        int swz = (f & 7) * 64 + (f >> 3);     // 512 = 8*64 bijective
        bz = swz >> 7; int rem = swz & 127;
        by = 15 - (rem >> 3); bx = rem & 7;    // long blocks at low f (LPT-ish)
    }

    const int tid = threadIdx.x;
    const int lane = tid & 63, wid = tid >> 6;
    const int wm = (NW == 8) ? (wid >> 2) : (wid >> 1);
    const int wc = wid & ((NW == 8) ? 3 : 1);

    const ushort_t* Ab = A + (size_t)bz * strideA;
    const ushort_t* Bb = Bt + (size_t)bz * strideB;

    __shared__ ushort_t As[3][128 * 32];
    __shared__ ushort_t Bs[3][BN * 32];

    const int brow = by * 128, bcol = bx * BN;

    int kEnd = K;
    if constexpr (MODE == 3) { int lim = (by + 1) * 128; kEnd = lim < K ? lim : K; }
    const int nt = kEnd / 32;

    v4f acc[4][4];
    #pragma unroll
    for (int mi = 0; mi < 4; ++mi)
        #pragma unroll
        for (int ni = 0; ni < 4; ++ni)
            acc[mi][ni] = (v4f)0.f;

    const int rr = tid >> 2, slot = tid & 3;
    auto STAGE = [&](int buf, int t) {
        const int k0 = t * 32;
        #pragma unroll
        for (int c = 0; c < ALINES; ++c) {
            int r = c * RPL + rr;
            int sc = ((slot ^ ((r >> 1) & 3)) << 3);
            load_lds16(Ab + (size_t)(brow + r) * lda + k0 + sc,
                       &As[buf][(size_t)(c * RPL + wid * 16) * 32]);
        }
        #pragma unroll
        for (int c = 0; c < BLINES; ++c) {
            int r = c * RPL + rr;
            int sc = ((slot ^ ((r >> 1) & 3)) << 3);
            load_lds16(Bb + (size_t)(bcol + r) * ldb + k0 + sc,
                       &Bs[buf][(size_t)(c * RPL + wid * 16) * 32]);
        }
    };

    const int frow = lane & 15, fq4 = lane >> 4;
    const int csw = ((fq4 ^ ((frow >> 1) & 3)) << 3);   // swizzled 16B slot

    STAGE(0, 0);
    if (nt > 1) STAGE(1, 1);

    int cur = 0;
    for (int t = 0; t < nt; ++t) {
        if (t + 2 < nt) {
            int tgt = cur ? cur - 1 : 2;       // (cur+2)%3
            STAGE(tgt, t + 2);
            if constexpr (MODE == 3) asm volatile("s_waitcnt vmcnt(8)" ::: "memory");
            else                     asm volatile("s_waitcnt vmcnt(6)" ::: "memory");
        } else if (t + 1 < nt) {
            if constexpr (MODE == 3) asm volatile("s_waitcnt vmcnt(4)" ::: "memory");
            else                     asm volatile("s_waitcnt vmcnt(3)" ::: "memory");
        } else {
            asm volatile("s_waitcnt vmcnt(0)" ::: "memory");
        }
        BAR();
        const ushort_t* Ac = &As[cur][0];
        const ushort_t* Bc = &Bs[cur][0];
        v8s a[4], b[4];
        #pragma unroll
        for (int mi = 0; mi < 4; ++mi)
            a[mi] = *(const v8s*)(Ac + (size_t)(wm * 64 + mi * 16 + frow) * 32 + csw);
        #pragma unroll
        for (int ni = 0; ni < 4; ++ni)
            b[ni] = *(const v8s*)(Bc + (size_t)(wc * 64 + ni * 16 + frow) * 32 + csw);
        __builtin_amdgcn_s_setprio(1);
        #pragma unroll
        for (int mi = 0; mi < 4; ++mi)
            #pragma unroll
            for (int ni = 0; ni < 4; ++ni)
                acc[mi][ni] = __builtin_amdgcn_mfma_f32_16x16x32_bf16(a[mi], b[ni], acc[mi][ni], 0, 0, 0);
        __builtin_amdgcn_s_setprio(0);
        BAR();
        cur = (cur == 2) ? 0 : cur + 1;
    }

    const int fr = lane & 15;
    const int fq = lane >> 4;

    if constexpr (MODE == 0) {
        const int route = bx >> 2;             // 0=Q, 1=K, 2=V (4 tiles each)
        const int cbase = (bx & 3) * 256 + wc * 64;
        if (route < 2) {
            ushort_t* C = route ? Kb : Qb;
            const float* bias = route ? bk : bq;
            const float scale = route ? 1.0f : 0.03125f;
            #pragma unroll
            for (int ni = 0; ni < 4; ++ni) {
                int cg = cbase + ni * 16 + fr;
                float bb = bias[cg];
                #pragma unroll
                for (int mi = 0; mi < 4; ++mi) {
                    int gr0 = brow + wm * 64 + mi * 16 + fq * 4;
                    #pragma unroll
                    for (int j = 0; j < 4; ++j)
                        C[(size_t)(gr0 + j) * 1024 + cg] = f2bf((acc[mi][ni][j] + bb) * scale);
                }
            }
        } else {
            #pragma unroll
            for (int ni = 0; ni < 4; ++ni) {
                int e = cbase + ni * 16 + fr;
                float bb = bv[e];
                #pragma unroll
                for (int mi = 0; mi < 4; ++mi) {
                    int gr0 = brow + wm * 64 + mi * 16 + fq * 4;   // b*2048 + s
                    int bbat = gr0 >> 11;
                    int sl2 = gr0 & 2047;
                    alignas(8) ushort_t tmp[4];
                    #pragma unroll
                    for (int j = 0; j < 4; ++j)
                        tmp[j] = f2bf(acc[mi][ni][j] + bb);
                    *(v4s*)(Vt + (size_t)bbat * (1024 * 2048) + (size_t)e * 2048 + sl2) =
                        *(const v4s*)tmp;
                }
            }
        }
    } else {
        float* C = Cf + (size_t)bz * strideC;
        #pragma unroll
        for (int ni = 0; ni < 4; ++ni) {
            int gc = bcol + wc * 64 + ni * 16 + fr;
            #pragma unroll
            for (int mi = 0; mi < 4; ++mi) {
                int gr0 = brow + wm * 64 + mi * 16 + fq * 4;
                #pragma unroll
                for (int j = 0; j < 4; ++j)
                    C[(size_t)(gr0 + j) * ldc + gc] = acc[mi][ni][j];
            }
        }
    }
}

// ---------------------------------------------------------------------------
// causal row softmax; fp32 scores row -> bf16 P in place (row pitch 4096 bf16).
// Writes zeros up to Lw = round-up-128(i+1) — PV K-limit granularity is 128.
__global__ __launch_bounds__(256) void softmax_causal(float* __restrict__ Sc) {
    int row = blockIdx.x;                // b*2048 + i
    int b = row >> 11, i = row & 2047;
    float* srow = Sc + ((size_t)b * 2048 + i) * 2048;
    const int L = i + 1;
    const int Lw = ((i >> 7) + 1) << 7;
    __shared__ float vals[2048];
    __shared__ float red[8];
    int tid = threadIdx.x, lane = tid & 63, wid = tid >> 6;

    float mx = -3.0e38f;
    const int L4 = L >> 2;
    for (int j = tid; j < L4; j += 256) {
        float4 v = ((const float4*)srow)[j];
        ((float4*)vals)[j] = v;
        mx = fmaxf(fmaxf(mx, fmaxf(v.x, v.y)), fmaxf(v.z, v.w));
    }
    {
        int j = (L4 << 2) + tid;
        if (j < L) { float v = srow[j]; vals[j] = v; mx = fmaxf(mx, v); }
    }
    #pragma unroll
    for (int o = 32; o; o >>= 1) mx = fmaxf(mx, __shfl_down(mx, o));
    if (lane == 0) red[wid] = mx;
    __syncthreads();
    mx = fmaxf(fmaxf(red[0], red[1]), fmaxf(red[2], red[3]));

    float sum = 0.f;
    for (int j = tid; j < L; j += 256) {
        float e = __expf(vals[j] - mx);
        vals[j] = e;
        sum += e;
    }
    #pragma unroll
    for (int o = 32; o; o >>= 1) sum += __shfl_down(sum, o);
    if (lane == 0) red[wid + 4] = sum;
    __syncthreads();
    float inv = 1.f / (red[4] + red[5] + red[6] + red[7]);

    ushort_t* prow = (ushort_t*)srow;
    for (int j4 = tid; j4 * 4 < Lw; j4 += 256) {
        int j = j4 * 4;
        float4 v = ((const float4*)vals)[j4];
        v4s p;
        p[0] = (short)f2bf((j     < L) ? v.x * inv : 0.f);
        p[1] = (short)f2bf((j + 1 < L) ? v.y * inv : 0.f);
        p[2] = (short)f2bf((j + 2 < L) ? v.z * inv : 0.f);
        p[3] = (short)f2bf((j + 3 < L) ? v.w * inv : 0.f);
        *(v4s*)(prow + j) = p;
    }
}

// ---------------------------------------------------------------------------
extern "C" void kernel_launch(void* const* d_in, const int* in_sizes, int n_in,
                              void* d_out, int out_size, void* d_ws, size_t ws_size,
                              hipStream_t stream) {
    const float* x  = (const float*)d_in[0];
    // d_in[1] = additive causal mask: structurally known, not read.
    const float* Wq = (const float*)d_in[2];
    const float* bq = (const float*)d_in[3];
    const float* Wk = (const float*)d_in[4];
    const float* bk = (const float*)d_in[5];
    const float* Wv = (const float*)d_in[6];
    const float* bv = (const float*)d_in[7];

    ushort_t* xb = (ushort_t*)d_ws;                        // 16.78 MB
    ushort_t* Wt = xb + (size_t)8192 * 1024;               //  6.29 MB (3x1024x1024)
    ushort_t* Qb = Wt + (size_t)3 * 1024 * 1024;           // 16.78 MB (scaled 1/32)
    ushort_t* Kb = Qb + (size_t)8192 * 1024;               // 16.78 MB
    ushort_t* Vt = Kb + (size_t)8192 * 1024;               // 16.78 MB (4x[1024][2048])
    float*    Sc = (float*)(Vt + (size_t)8192 * 1024);     // 67.11 MB

    cvt_kernel<<<2048, 256, 0, stream>>>((const float4*)x, xb, 8192 * 1024 / 4);
    transpose_w<<<dim3(32, 32, 3), dim3(32, 8), 0, stream>>>(Wq, Wk, Wv, Wt);

    // fused QKV projection: [8192x1024] x [3072x1024]^T
    gemm_ring<0><<<768, 512, 0, stream>>>(xb, 1024, 0, Wt, 1024, 0,
                                          bq, bk, bv, Qb, Kb, Vt,
                                          nullptr, 0, 0, 1024);

    // scores = Q K^T (causal, 128x256 tiles, 288 blocks)
    gemm_ring<2><<<288, 512, 0, stream>>>(Qb, 1024, 2048LL * 1024,
                                          Kb, 1024, 2048LL * 1024,
                                          nullptr, nullptr, nullptr,
                                          nullptr, nullptr, nullptr,
                                          Sc, 2048, 2048LL * 2048, 1024);

    softmax_causal<<<8192, 256, 0, stream>>>(Sc);

    // O = P V (128x128 tiles, 512 blocks, K limited per 128-row block)
    gemm_ring<3><<<512, 256, 0, stream>>>((const ushort_t*)Sc, 4096, 2048LL * 4096,
                                          Vt, 2048, 2048LL * 1024,
                                          nullptr, nullptr, nullptr,
                                          nullptr, nullptr, nullptr,
                                          (float*)d_out, 1024, 2048LL * 1024, 2048);
    (void)in_sizes; (void)n_in; (void)out_size; (void)ws_size;
}